// Round 1
// baseline (5941.086 us; speedup 1.0000x reference)
//
#include <hip/hip_runtime.h>
#include <cmath>

// Problem constants (from reference setup_inputs)
#define NB 32
#define NL 512
#define ND 768
#define NK 8192
#define NM (NB*NL)   // 16384 rows total

// ---------------------------------------------------------------------------
// Kernel 0: per-batch compaction of valid (mask==1) row indices.
// One block per b, 512 threads. valid_b[b*NL + i] = l indices, count_b[b].
// ---------------------------------------------------------------------------
__global__ __launch_bounds__(NL)
void compact_mask(const int* __restrict__ mask,
                  int* __restrict__ valid_b,
                  int* __restrict__ count_b) {
  int b = blockIdx.x;
  int t = threadIdx.x;                 // 0..511
  int v = (mask[b*NL + t] != 0) ? 1 : 0;
  unsigned long long bal = __ballot(v);
  int lane = t & 63;
  int wv = t >> 6;                     // wave id 0..7
  __shared__ int wcnt[8], woff[8];
  int pos = __popcll(bal & ((1ull << lane) - 1ull));
  if (lane == 0) wcnt[wv] = __popcll(bal);
  __syncthreads();
  if (t == 0) {
    int s = 0;
    for (int w = 0; w < 8; ++w) { woff[w] = s; s += wcnt[w]; }
    count_b[b] = s;
  }
  __syncthreads();
  if (v) valid_b[b*NL + woff[wv] + pos] = t;
}

// ---------------------------------------------------------------------------
// Pass 1: per valid row, online (m, Z) over a K-half. 64x128x16 tiles,
// 128 threads, 8x8 register blocking. Grid (8 ltiles, 32 b, 2 k-halves).
// ---------------------------------------------------------------------------
#define P1_BM 64
#define P1_BN 128
#define P1_BK 16
#define KSPLIT 2
#define KHALF (NK/KSPLIT)

__global__ __launch_bounds__(128)
void pass1_mz(const float* __restrict__ q, const float* __restrict__ p,
              const float* __restrict__ temp,
              const int* __restrict__ valid_b, const int* __restrict__ count_b,
              float* __restrict__ m_part, float* __restrict__ z_part) {
  int b = blockIdx.y;
  int cnt = count_b[b];
  int r0 = blockIdx.x * P1_BM;
  if (r0 >= cnt) return;
  int kh = blockIdx.z;
  int tid = threadIdx.x;
  int tx = tid & 15, ty = tid >> 4;    // tx: 16 col groups, ty: 8 row groups
  float invT = 1.0f / temp[0];

  __shared__ float Qs[P1_BK][P1_BM + 4];
  __shared__ float Bs[P1_BK][P1_BN + 4];
  __shared__ int rows[P1_BM];

  if (tid < P1_BM) {
    int pos = r0 + tid;
    rows[tid] = valid_b[b*NL + (pos < cnt ? pos : cnt - 1)];
  }
  __syncthreads();

  float mrun[8], zrun[8];
#pragma unroll
  for (int i = 0; i < 8; ++i) { mrun[i] = -INFINITY; zrun[i] = 0.f; }

  const float* qb = q + (size_t)b * NL * ND;

  for (int k0 = kh*KHALF; k0 < (kh+1)*KHALF; k0 += P1_BN) {
    float acc[8][8];
#pragma unroll
    for (int i = 0; i < 8; ++i)
#pragma unroll
      for (int j = 0; j < 8; ++j) acc[i][j] = 0.f;

    for (int d0 = 0; d0 < ND; d0 += P1_BK) {
      { // Q tile 64x16 -> Qs[dk][row]
        int dk = tid & 15, rg = tid >> 4;
#pragma unroll
        for (int ii = 0; ii < 8; ++ii) {
          int r = rg * 8 + ii;
          Qs[dk][r] = qb[(size_t)rows[r] * ND + d0 + dk];
        }
      }
      { // B tile 128x16 -> Bs[dk][n]
        int dk = tid & 15, ng = tid >> 4;
        const float* pb = p + (size_t)(k0 + ng*16) * ND + d0 + dk;
#pragma unroll
        for (int jj = 0; jj < 16; ++jj)
          Bs[dk][ng*16 + jj] = pb[(size_t)jj * ND];
      }
      __syncthreads();
#pragma unroll
      for (int dk = 0; dk < P1_BK; ++dk) {
        float4 qa  = *(const float4*)&Qs[dk][ty*8];
        float4 qc  = *(const float4*)&Qs[dk][ty*8+4];
        float4 b0  = *(const float4*)&Bs[dk][tx*8];
        float4 b1  = *(const float4*)&Bs[dk][tx*8+4];
        float qv[8] = {qa.x,qa.y,qa.z,qa.w,qc.x,qc.y,qc.z,qc.w};
        float bv[8] = {b0.x,b0.y,b0.z,b0.w,b1.x,b1.y,b1.z,b1.w};
#pragma unroll
        for (int i = 0; i < 8; ++i)
#pragma unroll
          for (int j = 0; j < 8; ++j)
            acc[i][j] = fmaf(qv[i], bv[j], acc[i][j]);
      }
      __syncthreads();
    }
    // online softmax update for this 128-wide k-tile
#pragma unroll
    for (int i = 0; i < 8; ++i) {
      float x[8], tmax = -INFINITY;
#pragma unroll
      for (int j = 0; j < 8; ++j) { x[j] = acc[i][j] * invT; tmax = fmaxf(tmax, x[j]); }
#pragma unroll
      for (int o = 1; o < 16; o <<= 1) tmax = fmaxf(tmax, __shfl_xor(tmax, o));
      float mnew = fmaxf(mrun[i], tmax);
      float s = 0.f;
#pragma unroll
      for (int j = 0; j < 8; ++j) s += __expf(x[j] - mnew);
#pragma unroll
      for (int o = 1; o < 16; o <<= 1) s += __shfl_xor(s, o);
      zrun[i] = zrun[i] * __expf(mrun[i] - mnew) + s;
      mrun[i] = mnew;
    }
  }
  if (tx == 0) {
#pragma unroll
    for (int i = 0; i < 8; ++i) {
      int slot = ty*8 + i;
      if (r0 + slot < cnt) {
        int l = rows[slot];
        m_part[(size_t)kh*NM + b*NL + l] = mrun[i];
        z_part[(size_t)kh*NM + b*NL + l] = zrun[i];
      }
    }
  }
}

// ---------------------------------------------------------------------------
// Combine the two K-half (m,Z) partials -> m, 1/Z per row.
// ---------------------------------------------------------------------------
__global__ __launch_bounds__(256)
void combine_mz(const float* __restrict__ m_part, const float* __restrict__ z_part,
                float* __restrict__ m_out, float* __restrict__ iz_out) {
  int r = blockIdx.x * blockDim.x + threadIdx.x;
  if (r >= NM) return;
  float m0 = m_part[r],      m1 = m_part[NM + r];
  float z0 = z_part[r],      z1 = z_part[NM + r];
  float m = fmaxf(m0, m1);
  float z = z0 * __expf(m0 - m) + z1 * __expf(m1 - m);
  m_out[r] = m;
  iz_out[r] = 1.0f / z;
}

// ---------------------------------------------------------------------------
// Pass 2: per (b, 128-wide k-tile), loop valid rows in 64-row tiles,
// recompute logits, A = exp(x-m)*invZ, column-max -> out (unnormalized).
// ---------------------------------------------------------------------------
#define P2_BM 64
#define P2_BN 128
#define P2_BK 16

__global__ __launch_bounds__(128)
void pass2_smax(const float* __restrict__ q, const float* __restrict__ p,
                const float* __restrict__ temp,
                const int* __restrict__ valid_b, const int* __restrict__ count_b,
                const float* __restrict__ m_in, const float* __restrict__ iz_in,
                float* __restrict__ out) {
  int b = blockIdx.y;
  int k0 = blockIdx.x * P2_BN;
  int cnt = count_b[b];
  int tid = threadIdx.x;
  int tx = tid & 15, ty = tid >> 4;
  float invT = 1.0f / temp[0];

  __shared__ float Qs[P2_BK][P2_BM + 4];
  __shared__ float Bs[P2_BK][P2_BN + 4];
  __shared__ int   rows[P2_BM];
  __shared__ float mrow[P2_BM], izrow[P2_BM];
  __shared__ float red[8][P2_BN + 4];

  const float* qb = q + (size_t)b * NL * ND;
  float rcmax[8];
#pragma unroll
  for (int j = 0; j < 8; ++j) rcmax[j] = 0.f;

  for (int t0 = 0; t0 < cnt; t0 += P2_BM) {
    if (tid < P2_BM) {
      int pos = t0 + tid;
      int l = valid_b[b*NL + (pos < cnt ? pos : cnt - 1)];
      rows[tid] = l;
      mrow[tid] = m_in[b*NL + l];
      izrow[tid] = (pos < cnt) ? iz_in[b*NL + l] : 0.f;   // pad rows contribute 0
    }
    __syncthreads();

    float acc[8][8];
#pragma unroll
    for (int i = 0; i < 8; ++i)
#pragma unroll
      for (int j = 0; j < 8; ++j) acc[i][j] = 0.f;

    for (int d0 = 0; d0 < ND; d0 += P2_BK) {
      {
        int dk = tid & 15, rg = tid >> 4;
#pragma unroll
        for (int ii = 0; ii < 8; ++ii) {
          int r = rg * 8 + ii;
          Qs[dk][r] = qb[(size_t)rows[r] * ND + d0 + dk];
        }
      }
      {
        int dk = tid & 15, ng = tid >> 4;
        const float* pb = p + (size_t)(k0 + ng*16) * ND + d0 + dk;
#pragma unroll
        for (int jj = 0; jj < 16; ++jj)
          Bs[dk][ng*16 + jj] = pb[(size_t)jj * ND];
      }
      __syncthreads();
#pragma unroll
      for (int dk = 0; dk < P2_BK; ++dk) {
        float4 qa  = *(const float4*)&Qs[dk][ty*8];
        float4 qc  = *(const float4*)&Qs[dk][ty*8+4];
        float4 b0  = *(const float4*)&Bs[dk][tx*8];
        float4 b1  = *(const float4*)&Bs[dk][tx*8+4];
        float qv[8] = {qa.x,qa.y,qa.z,qa.w,qc.x,qc.y,qc.z,qc.w};
        float bv[8] = {b0.x,b0.y,b0.z,b0.w,b1.x,b1.y,b1.z,b1.w};
#pragma unroll
        for (int i = 0; i < 8; ++i)
#pragma unroll
          for (int j = 0; j < 8; ++j)
            acc[i][j] = fmaf(qv[i], bv[j], acc[i][j]);
      }
      __syncthreads();
    }

#pragma unroll
    for (int i = 0; i < 8; ++i) {
      float mi  = mrow[ty*8+i];
      float izi = izrow[ty*8+i];
#pragma unroll
      for (int j = 0; j < 8; ++j) {
        float a = __expf(acc[i][j]*invT - mi) * izi;
        rcmax[j] = fmaxf(rcmax[j], a);
      }
    }
    __syncthreads();   // protect rows/mrow/izrow before next tile overwrites
  }

  // reduce partial col-max across the 8 ty groups
#pragma unroll
  for (int j = 0; j < 8; ++j) red[ty][tx*8+j] = rcmax[j];
  __syncthreads();
  {
    float v = red[0][tid];
#pragma unroll
    for (int w = 1; w < 8; ++w) v = fmaxf(v, red[w][tid]);
    out[(size_t)b*NK + k0 + tid] = v;
  }
}

// ---------------------------------------------------------------------------
// Kernel 4: L2-normalize each batch row of out (length NK), torch-eps clamp.
// ---------------------------------------------------------------------------
__global__ __launch_bounds__(256)
void normalize_rows(float* __restrict__ out) {
  int b = blockIdx.x;
  int tid = threadIdx.x;
  float* row = out + (size_t)b*NK;
  float ss = 0.f;
  for (int i = tid; i < NK; i += 256) { float v = row[i]; ss = fmaf(v, v, ss); }
#pragma unroll
  for (int o = 1; o < 64; o <<= 1) ss += __shfl_xor(ss, o);
  __shared__ float wsum[4];
  int lane = tid & 63, wv = tid >> 6;
  if (lane == 0) wsum[wv] = ss;
  __syncthreads();
  float tot = wsum[0] + wsum[1] + wsum[2] + wsum[3];
  float norm = sqrtf(tot);
  float inv = 1.0f / fmaxf(norm, 1e-12f);
  for (int i = tid; i < NK; i += 256) row[i] *= inv;
}

// ---------------------------------------------------------------------------
extern "C" void kernel_launch(void* const* d_in, const int* in_sizes, int n_in,
                              void* d_out, int out_size, void* d_ws, size_t ws_size,
                              hipStream_t stream) {
  const float* q    = (const float*)d_in[0];   // (32,512,768)
  const float* p    = (const float*)d_in[1];   // (8192,768)
  const float* temp = (const float*)d_in[2];   // scalar
  const int*   mask = (const int*)d_in[3];     // (32,512)
  float* out = (float*)d_out;                  // (32,8192)

  // workspace layout (floats): m[NM] | invZ[NM] | m_part[2*NM] | z_part[2*NM]
  // then ints: valid_b[NM] | count_b[NB]  -> ~449 KB total
  float* wsf    = (float*)d_ws;
  float* m_arr  = wsf;
  float* iz_arr = wsf + NM;
  float* m_part = wsf + 2*NM;
  float* z_part = wsf + 4*NM;
  int*   vb     = (int*)(wsf + 6*NM);
  int*   cb     = vb + NM;

  compact_mask<<<NB, NL, 0, stream>>>(mask, vb, cb);

  dim3 g1(NL/P1_BM, NB, KSPLIT);
  pass1_mz<<<g1, 128, 0, stream>>>(q, p, temp, vb, cb, m_part, z_part);

  combine_mz<<<(NM + 255)/256, 256, 0, stream>>>(m_part, z_part, m_arr, iz_arr);

  dim3 g2(NK/P2_BN, NB);
  pass2_smax<<<g2, 128, 0, stream>>>(q, p, temp, vb, cb, m_arr, iz_arr, out);

  normalize_rows<<<NB, 256, 0, stream>>>(out);
}

// Round 2
// 1289.545 us; speedup vs baseline: 4.6071x; 4.6071x over previous
//
#include <hip/hip_runtime.h>
#include <cmath>

#define NB 32
#define NL 512
#define ND 768
#define NK 8192
#define NM (NB*NL)      // 16384 rows
#define BM 128
#define BN 128
#define KSPLIT 8
#define KSLICE (NK/KSPLIT)   // 1024

typedef __attribute__((ext_vector_type(8))) short bf16x8;
typedef __attribute__((ext_vector_type(4))) float f32x4;

// Split fp32 x into hi+lo bf16 pair (packed 2-at-a-time via v_cvt_pk_bf16_f32).
// h/l each hold two packed bf16: low16 = cvt(x0), high16 = cvt(x1).
__device__ __forceinline__ void split_pk(float x0, float x1, unsigned &h, unsigned &l) {
  unsigned hp;
  asm("v_cvt_pk_bf16_f32 %0, %1, %2" : "=v"(hp) : "v"(x0), "v"(x1));
  union { unsigned u; float f; } f0, f1;
  f0.u = hp << 16;
  f1.u = hp & 0xffff0000u;
  unsigned lp;
  float r0 = x0 - f0.f, r1 = x1 - f1.f;
  asm("v_cvt_pk_bf16_f32 %0, %1, %2" : "=v"(lp) : "v"(r0), "v"(r1));
  h = hp; l = lp;
}

// Convert 16 staged floats -> hi/lo bf16 tiles, write 16B-vector LDS stores.
// LDS row stride 40 shorts (80B): bank-uniform for b128 reads & writes.
__device__ __forceinline__ void cvtstore(const float4* v,
                                         unsigned short (*H)[40], unsigned short (*L)[40],
                                         int trow, int cofs) {
  unsigned h[8], l[8];
  split_pk(v[0].x, v[0].y, h[0], l[0]); split_pk(v[0].z, v[0].w, h[1], l[1]);
  split_pk(v[1].x, v[1].y, h[2], l[2]); split_pk(v[1].z, v[1].w, h[3], l[3]);
  split_pk(v[2].x, v[2].y, h[4], l[4]); split_pk(v[2].z, v[2].w, h[5], l[5]);
  split_pk(v[3].x, v[3].y, h[6], l[6]); split_pk(v[3].z, v[3].w, h[7], l[7]);
  *(uint4*)&H[trow][cofs]     = make_uint4(h[0], h[1], h[2], h[3]);
  *(uint4*)&H[trow][cofs + 8] = make_uint4(h[4], h[5], h[6], h[7]);
  *(uint4*)&L[trow][cofs]     = make_uint4(l[0], l[1], l[2], l[3]);
  *(uint4*)&L[trow][cofs + 8] = make_uint4(l[4], l[5], l[6], l[7]);
}

// One BK=32 step: 16 frag loads, 48 MFMAs (3-product split-bf16).
__device__ __forceinline__ void mfma_step(const unsigned short (*AH)[40], const unsigned short (*AL)[40],
                                          const unsigned short (*BH)[40], const unsigned short (*BL)[40],
                                          int wm, int wn, int fr, int fq, f32x4 acc[4][4]) {
  bf16x8 aH[4], aL[4], bH[4], bL[4];
#pragma unroll
  for (int i = 0; i < 4; ++i) {
    aH[i] = *(const bf16x8*)&AH[wm*64 + i*16 + fr][fq*8];
    aL[i] = *(const bf16x8*)&AL[wm*64 + i*16 + fr][fq*8];
    bH[i] = *(const bf16x8*)&BH[wn*64 + i*16 + fr][fq*8];
    bL[i] = *(const bf16x8*)&BL[wn*64 + i*16 + fr][fq*8];
  }
#pragma unroll
  for (int mi = 0; mi < 4; ++mi)
#pragma unroll
    for (int ni = 0; ni < 4; ++ni) {
      acc[mi][ni] = __builtin_amdgcn_mfma_f32_16x16x32_bf16(aH[mi], bH[ni], acc[mi][ni], 0, 0, 0);
      acc[mi][ni] = __builtin_amdgcn_mfma_f32_16x16x32_bf16(aH[mi], bL[ni], acc[mi][ni], 0, 0, 0);
      acc[mi][ni] = __builtin_amdgcn_mfma_f32_16x16x32_bf16(aL[mi], bH[ni], acc[mi][ni], 0, 0, 0);
    }
}

// ---------------------------------------------------------------------------
// Kernel 0: global compaction of valid rows across ALL batches.
// vg[j] = b*NL + l for j-th valid row (batch-major); cntb/offb per batch; total.
// ---------------------------------------------------------------------------
__global__ __launch_bounds__(512)
void compact_all(const int* __restrict__ mask, int* __restrict__ vg,
                 int* __restrict__ cntb, int* __restrict__ offb,
                 int* __restrict__ total) {
  __shared__ int wcnt[8], woff[8];
  __shared__ int base;
  int t = threadIdx.x;
  if (t == 0) base = 0;
  __syncthreads();
  for (int b = 0; b < NB; ++b) {
    int v = (mask[b*NL + t] != 0) ? 1 : 0;
    unsigned long long bal = __ballot(v);
    int lane = t & 63, wv = t >> 6;
    int pos = __popcll(bal & ((1ull << lane) - 1ull));
    if (lane == 0) wcnt[wv] = __popcll(bal);
    __syncthreads();
    if (t == 0) {
      int s = 0;
#pragma unroll
      for (int w = 0; w < 8; ++w) { woff[w] = s; s += wcnt[w]; }
      cntb[b] = s; offb[b] = base;
    }
    __syncthreads();
    if (v) vg[base + woff[wv] + pos] = b*NL + t;
    __syncthreads();
    if (t == 0) base += cntb[b];
    __syncthreads();
  }
  if (t == 0) total[0] = base;
}

// ---------------------------------------------------------------------------
// Pass 1: per-row online (m, Z) over a 1024-wide k-slice. MFMA split-bf16.
// Grid (128 row-tiles [early-exit], KSPLIT). 256 threads, 4 waves 2x2.
// ---------------------------------------------------------------------------
__global__ __launch_bounds__(256, 2)
void pass1(const float* __restrict__ q, const float* __restrict__ p,
           const float* __restrict__ temp, const int* __restrict__ vg,
           const int* __restrict__ total_p,
           float* __restrict__ m_part, float* __restrict__ z_part) {
  int total = total_p[0];
  int row0 = blockIdx.x * BM;
  if (row0 >= total) return;
  int kh = blockIdx.y;
  int tid = threadIdx.x;

  __shared__ unsigned short AsH[BM][40], AsL[BM][40], BsH[BN][40], BsL[BN][40];
  __shared__ int rows_s[BM];
  __shared__ float mloc[2][BM], zloc[2][BM];

  float invT = 1.0f / temp[0];
  if (tid < BM) rows_s[tid] = vg[min(row0 + tid, total - 1)];
  __syncthreads();

  int trow = tid & 127, hsel = tid >> 7;
  int wid = tid >> 6, lane = tid & 63;
  int wm = wid >> 1, wn = wid & 1;
  int fr = lane & 15, fq = lane >> 4;
  const float* qbase = q + (size_t)rows_s[trow] * ND + hsel * 16;

  float mrun = -INFINITY, zrun = 0.f;   // meaningful for tid < BM

  for (int kt = 0; kt < KSLICE/BN; ++kt) {
    int k0 = kh * KSLICE + kt * BN;
    const float* pbase = p + (size_t)(k0 + trow) * ND + hsel * 16;
    f32x4 acc[4][4];
#pragma unroll
    for (int i = 0; i < 4; ++i)
#pragma unroll
      for (int j = 0; j < 4; ++j) acc[i][j] = f32x4{0.f, 0.f, 0.f, 0.f};

    for (int d0 = 0; d0 < ND; d0 += 32) {
      float4 qv[4], pv[4];
#pragma unroll
      for (int c = 0; c < 4; ++c) qv[c] = *(const float4*)(qbase + d0 + c*4);
#pragma unroll
      for (int c = 0; c < 4; ++c) pv[c] = *(const float4*)(pbase + d0 + c*4);
      __syncthreads();                       // prev frag reads done
      cvtstore(qv, AsH, AsL, trow, hsel*16);
      cvtstore(pv, BsH, BsL, trow, hsel*16);
      __syncthreads();                       // tiles visible
      mfma_step(AsH, AsL, BsH, BsL, wm, wn, fr, fq, acc);
    }

#pragma unroll
    for (int i = 0; i < 4; ++i)
#pragma unroll
      for (int j = 0; j < 4; ++j) acc[i][j] *= invT;

    // per-row (max, sumexp) within this 128-wide tile
#pragma unroll
    for (int mi = 0; mi < 4; ++mi)
#pragma unroll
      for (int r = 0; r < 4; ++r) {
        float vm = -INFINITY;
#pragma unroll
        for (int ni = 0; ni < 4; ++ni) vm = fmaxf(vm, acc[mi][ni][r]);
        vm = fmaxf(vm, __shfl_xor(vm, 1));
        vm = fmaxf(vm, __shfl_xor(vm, 2));
        vm = fmaxf(vm, __shfl_xor(vm, 4));
        vm = fmaxf(vm, __shfl_xor(vm, 8));
        float s = 0.f;
#pragma unroll
        for (int ni = 0; ni < 4; ++ni) s += __expf(acc[mi][ni][r] - vm);
        s += __shfl_xor(s, 1); s += __shfl_xor(s, 2);
        s += __shfl_xor(s, 4); s += __shfl_xor(s, 8);
        if (fr == 0) {
          int slot = wm*64 + mi*16 + fq*4 + r;
          mloc[wn][slot] = vm; zloc[wn][slot] = s;
        }
      }
    __syncthreads();
    if (tid < BM) {   // merge wn halves, then into running state
      float m0 = mloc[0][tid], m1 = mloc[1][tid];
      float z0 = zloc[0][tid], z1 = zloc[1][tid];
      float mw = fmaxf(m0, m1);
      float zw = z0 * __expf(m0 - mw) + z1 * __expf(m1 - mw);
      float mn = fmaxf(mrun, mw);
      zrun = zrun * __expf(mrun - mn) + zw * __expf(mw - mn);
      mrun = mn;
    }
  }

  if (tid < BM && row0 + tid < total) {
    int gr = rows_s[tid];
    m_part[(size_t)kh * NM + gr] = mrun;
    z_part[(size_t)kh * NM + gr] = zrun;
  }
}

// ---------------------------------------------------------------------------
// Combine KSPLIT partials -> m, 1/Z per row (garbage for invalid rows, unused).
// ---------------------------------------------------------------------------
__global__ __launch_bounds__(256)
void combine(const float* __restrict__ m_part, const float* __restrict__ z_part,
             float* __restrict__ m_arr, float* __restrict__ iz_arr) {
  int r = blockIdx.x * 256 + threadIdx.x;
  if (r >= NM) return;
  float m = -INFINITY;
#pragma unroll
  for (int k = 0; k < KSPLIT; ++k) m = fmaxf(m, m_part[(size_t)k*NM + r]);
  float z = 0.f;
#pragma unroll
  for (int k = 0; k < KSPLIT; ++k)
    z += z_part[(size_t)k*NM + r] * __expf(m_part[(size_t)k*NM + r] - m);
  m_arr[r] = m;
  iz_arr[r] = 1.0f / z;
}

// ---------------------------------------------------------------------------
// Pass 2: per (k-tile, b): recompute logits over batch's valid rows,
// A = exp(x - m)/Z, column-max -> out (unnormalized). Duplicate-row padding
// is benign under max (pads get iz=0).
// ---------------------------------------------------------------------------
__global__ __launch_bounds__(256, 2)
void pass2(const float* __restrict__ q, const float* __restrict__ p,
           const float* __restrict__ temp, const int* __restrict__ vg,
           const int* __restrict__ cntb, const int* __restrict__ offb,
           const float* __restrict__ m_arr, const float* __restrict__ iz_arr,
           float* __restrict__ out) {
  int b = blockIdx.y;
  int k0 = blockIdx.x * BN;
  int cb = cntb[b], ob = offb[b];
  int tid = threadIdx.x;

  __shared__ unsigned short AsH[BM][40], AsL[BM][40], BsH[BN][40], BsL[BN][40];
  __shared__ int rows_s[BM];
  __shared__ float mrow_s[BM], izrow_s[BM];
  __shared__ float red[2][BN];

  float invT = 1.0f / temp[0];
  int trow = tid & 127, hsel = tid >> 7;
  int wid = tid >> 6, lane = tid & 63;
  int wm = wid >> 1, wn = wid & 1;
  int fr = lane & 15, fq = lane >> 4;
  const float* pbase = p + (size_t)(k0 + trow) * ND + hsel * 16;
  float rc[4] = {0.f, 0.f, 0.f, 0.f};

  for (int t0 = 0; t0 < cb; t0 += BM) {
    if (tid < BM) {
      int j = min(t0 + tid, cb - 1);
      int gr = vg[ob + j];
      rows_s[tid] = gr;
      mrow_s[tid] = m_arr[gr];
      izrow_s[tid] = (t0 + tid < cb) ? iz_arr[gr] : 0.f;
    }
    __syncthreads();
    const float* qbase = q + (size_t)rows_s[trow] * ND + hsel * 16;

    f32x4 acc[4][4];
#pragma unroll
    for (int i = 0; i < 4; ++i)
#pragma unroll
      for (int j = 0; j < 4; ++j) acc[i][j] = f32x4{0.f, 0.f, 0.f, 0.f};

    for (int d0 = 0; d0 < ND; d0 += 32) {
      float4 qv[4], pv[4];
#pragma unroll
      for (int c = 0; c < 4; ++c) qv[c] = *(const float4*)(qbase + d0 + c*4);
#pragma unroll
      for (int c = 0; c < 4; ++c) pv[c] = *(const float4*)(pbase + d0 + c*4);
      __syncthreads();
      cvtstore(qv, AsH, AsL, trow, hsel*16);
      cvtstore(pv, BsH, BsL, trow, hsel*16);
      __syncthreads();
      mfma_step(AsH, AsL, BsH, BsL, wm, wn, fr, fq, acc);
    }

#pragma unroll
    for (int i = 0; i < 4; ++i)
#pragma unroll
      for (int j = 0; j < 4; ++j) acc[i][j] *= invT;

#pragma unroll
    for (int mi = 0; mi < 4; ++mi)
#pragma unroll
      for (int r = 0; r < 4; ++r) {
        int slot = wm*64 + mi*16 + fq*4 + r;
        float mv = mrow_s[slot], izv = izrow_s[slot];
#pragma unroll
        for (int ni = 0; ni < 4; ++ni)
          rc[ni] = fmaxf(rc[ni], __expf(acc[mi][ni][r] - mv) * izv);
      }
    __syncthreads();   // protect rows_s/mrow_s/As/Bs before next row-tile
  }

  // reduce col-max across fq row-groups, then across wm waves via LDS
#pragma unroll
  for (int ni = 0; ni < 4; ++ni) {
    rc[ni] = fmaxf(rc[ni], __shfl_xor(rc[ni], 16));
    rc[ni] = fmaxf(rc[ni], __shfl_xor(rc[ni], 32));
  }
  if (fq == 0) {
#pragma unroll
    for (int ni = 0; ni < 4; ++ni) red[wm][wn*64 + ni*16 + fr] = rc[ni];
  }
  __syncthreads();
  if (tid < BN) out[(size_t)b * NK + k0 + tid] = fmaxf(red[0][tid], red[1][tid]);
}

// ---------------------------------------------------------------------------
// L2-normalize each batch row (length NK), torch-eps clamp.
// ---------------------------------------------------------------------------
__global__ __launch_bounds__(256)
void normalize_rows(float* __restrict__ out) {
  int b = blockIdx.x;
  int tid = threadIdx.x;
  float* row = out + (size_t)b * NK;
  float ss = 0.f;
  for (int i = tid; i < NK; i += 256) { float v = row[i]; ss = fmaf(v, v, ss); }
#pragma unroll
  for (int o = 1; o < 64; o <<= 1) ss += __shfl_xor(ss, o);
  __shared__ float wsum[4];
  int lane = tid & 63, wv = tid >> 6;
  if (lane == 0) wsum[wv] = ss;
  __syncthreads();
  float tot = wsum[0] + wsum[1] + wsum[2] + wsum[3];
  float inv = 1.0f / fmaxf(sqrtf(tot), 1e-12f);
  for (int i = tid; i < NK; i += 256) row[i] *= inv;
}

// ---------------------------------------------------------------------------
extern "C" void kernel_launch(void* const* d_in, const int* in_sizes, int n_in,
                              void* d_out, int out_size, void* d_ws, size_t ws_size,
                              hipStream_t stream) {
  const float* q    = (const float*)d_in[0];
  const float* p    = (const float*)d_in[1];
  const float* temp = (const float*)d_in[2];
  const int*   mask = (const int*)d_in[3];
  float* out = (float*)d_out;

  // ws floats: m[NM] | iz[NM] | m_part[8*NM] | z_part[8*NM]  then ints:
  // vg[NM] | cntb[NB] | offb[NB] | total[1]   (~1.25 MB)
  float* wsf    = (float*)d_ws;
  float* m_arr  = wsf;
  float* iz_arr = wsf + NM;
  float* m_part = wsf + 2*NM;
  float* z_part = wsf + 2*NM + (size_t)KSPLIT*NM;
  int*   vg     = (int*)(wsf + 2*NM + (size_t)2*KSPLIT*NM);
  int*   cntb   = vg + NM;
  int*   offb   = cntb + NB;
  int*   total  = offb + NB;

  compact_all<<<1, 512, 0, stream>>>(mask, vg, cntb, offb, total);

  pass1<<<dim3(NM/BM, KSPLIT), 256, 0, stream>>>(q, p, temp, vg, total, m_part, z_part);

  combine<<<NM/256, 256, 0, stream>>>(m_part, z_part, m_arr, iz_arr);

  pass2<<<dim3(NK/BN, NB), 256, 0, stream>>>(q, p, temp, vg, cntb, offb, m_arr, iz_arr, out);

  normalize_rows<<<NB, 256, 0, stream>>>(out);
}

// Round 4
// 773.407 us; speedup vs baseline: 7.6817x; 1.6674x over previous
//
#include <hip/hip_runtime.h>
#include <cmath>

#define NB 32
#define NL 512
#define ND 768
#define NK 8192
#define NM (NB*NL)        // 16384 max rows
#define BM 128
#define BN 128
#define NDSTEP (ND/32)    // 24 d-steps of BK=32
#define KSPLIT 16
#define KSLICE (NK/KSPLIT)   // 512 -> 4 column tiles of 128 per pass1 block

typedef __attribute__((ext_vector_type(8))) short bf16x8;
typedef __attribute__((ext_vector_type(4))) float f32x4;
typedef unsigned short u16;

// async global->LDS, 16B per lane. dest must be wave-uniform; HW adds lane*16.
__device__ __forceinline__ void gload16(const void* g, void* s) {
  __builtin_amdgcn_global_load_lds(
      (const __attribute__((address_space(1))) char*)g,
      (__attribute__((address_space(3))) char*)s, 16, 0, 0);
}

// split fp32 pair into hi/lo bf16 pairs (packed)
__device__ __forceinline__ void split_pk(float x0, float x1, unsigned &h, unsigned &l) {
  unsigned hp;
  asm("v_cvt_pk_bf16_f32 %0, %1, %2" : "=v"(hp) : "v"(x0), "v"(x1));
  union { unsigned u; float f; } f0, f1;
  f0.u = hp << 16;
  f1.u = hp & 0xffff0000u;
  unsigned lp;
  float r0 = x0 - f0.f, r1 = x1 - f1.f;
  asm("v_cvt_pk_bf16_f32 %0, %1, %2" : "=v"(lp) : "v"(r0), "v"(r1));
  h = hp; l = lp;
}

// One BK=32 step: 16 ds_read_b128 + 48 MFMAs (3-product split-bf16).
// psl = fq ^ ((fr>>1)&3) : physical slot for this lane's logical k-slot fq.
__device__ __forceinline__ void mfma_step(const u16* Ah, const u16* Al,
                                          const u16* Bh, const u16* Bl,
                                          int wm, int wn, int fr, int psl,
                                          f32x4 acc[4][4]) {
  bf16x8 aH[4], aL[4], bH[4], bL[4];
#pragma unroll
  for (int i = 0; i < 4; ++i) {
    int ar = (wm*64 + i*16 + fr)*32 + psl*8;
    int br = (wn*64 + i*16 + fr)*32 + psl*8;
    aH[i] = *(const bf16x8*)&Ah[ar];
    aL[i] = *(const bf16x8*)&Al[ar];
    bH[i] = *(const bf16x8*)&Bh[br];
    bL[i] = *(const bf16x8*)&Bl[br];
  }
#pragma unroll
  for (int mi = 0; mi < 4; ++mi)
#pragma unroll
    for (int ni = 0; ni < 4; ++ni) {
      acc[mi][ni] = __builtin_amdgcn_mfma_f32_16x16x32_bf16(aH[mi], bH[ni], acc[mi][ni], 0, 0, 0);
      acc[mi][ni] = __builtin_amdgcn_mfma_f32_16x16x32_bf16(aH[mi], bL[ni], acc[mi][ni], 0, 0, 0);
      acc[mi][ni] = __builtin_amdgcn_mfma_f32_16x16x32_bf16(aL[mi], bH[ni], acc[mi][ni], 0, 0, 0);
    }
}

// ---------------------------------------------------------------------------
// Kernel 0: global compaction of valid rows (batch-major).
// ---------------------------------------------------------------------------
__global__ __launch_bounds__(512)
void compact_all(const int* __restrict__ mask, int* __restrict__ vg,
                 int* __restrict__ cntb, int* __restrict__ offb,
                 int* __restrict__ total) {
  __shared__ int wcnt[8], woff[8];
  __shared__ int base;
  int t = threadIdx.x;
  if (t == 0) base = 0;
  __syncthreads();
  for (int b = 0; b < NB; ++b) {
    int v = (mask[b*NL + t] != 0) ? 1 : 0;
    unsigned long long bal = __ballot(v);
    int lane = t & 63, wv = t >> 6;
    int pos = __popcll(bal & ((1ull << lane) - 1ull));
    if (lane == 0) wcnt[wv] = __popcll(bal);
    __syncthreads();
    if (t == 0) {
      int s = 0;
#pragma unroll
      for (int w = 0; w < 8; ++w) { woff[w] = s; s += wcnt[w]; }
      cntb[b] = s; offb[b] = base;
    }
    __syncthreads();
    if (v) vg[base + woff[wv] + pos] = b*NL + t;
    __syncthreads();
    if (t == 0) base += cntb[b];
    __syncthreads();
  }
  if (t == 0) total[0] = base;
}

// ---------------------------------------------------------------------------
// Convert Q -> compacted-row-major bf16 hi/lo. Plain layout (swizzle applied
// at stage time via per-lane source addressing).
// ---------------------------------------------------------------------------
__global__ __launch_bounds__(256)
void convert_q(const float* __restrict__ q, const int* __restrict__ vg,
               const int* __restrict__ total_p,
               u16* __restrict__ Qh, u16* __restrict__ Ql) {
  int total = total_p[0];
  int cid = blockIdx.x * 256 + threadIdx.x;       // chunk of 8 elements
  int row = cid / (ND/8), c = cid % (ND/8);
  if (row >= total) return;
  const float* src = q + (size_t)vg[row] * ND + c*8;
  float4 v0 = ((const float4*)src)[0], v1 = ((const float4*)src)[1];
  unsigned h[4], l[4];
  split_pk(v0.x, v0.y, h[0], l[0]); split_pk(v0.z, v0.w, h[1], l[1]);
  split_pk(v1.x, v1.y, h[2], l[2]); split_pk(v1.z, v1.w, h[3], l[3]);
  size_t o = (size_t)row * ND + c*8;
  *(uint4*)(Qh + o) = make_uint4(h[0], h[1], h[2], h[3]);
  *(uint4*)(Ql + o) = make_uint4(l[0], l[1], l[2], l[3]);
}

// ---------------------------------------------------------------------------
// Convert P -> tiled + pre-swizzled bf16 hi/lo.
// Tile (kt, dt) = 128 rows x 32 d, stored as 512 chunks of 16B; chunk
// (r, s_phys) holds logical d-slot s_phys ^ ((r>>1)&3).
// ---------------------------------------------------------------------------
__global__ __launch_bounds__(256)
void convert_p(const float* __restrict__ p,
               u16* __restrict__ Pht, u16* __restrict__ Plt) {
  int cid = blockIdx.x * 256 + threadIdx.x;        // 64*24*512 chunks
  int kt = cid / (NDSTEP*512);
  int rem = cid % (NDSTEP*512);
  int dt = rem / 512, c = rem % 512;
  int r = c >> 2, sp = c & 3;
  int sl = sp ^ ((r >> 1) & 3);
  const float* src = p + (size_t)(kt*128 + r) * ND + dt*32 + sl*8;
  float4 v0 = ((const float4*)src)[0], v1 = ((const float4*)src)[1];
  unsigned h[4], l[4];
  split_pk(v0.x, v0.y, h[0], l[0]); split_pk(v0.z, v0.w, h[1], l[1]);
  split_pk(v1.x, v1.y, h[2], l[2]); split_pk(v1.z, v1.w, h[3], l[3]);
  size_t o = (size_t)cid * 8;
  *(uint4*)(Pht + o) = make_uint4(h[0], h[1], h[2], h[3]);
  *(uint4*)(Plt + o) = make_uint4(l[0], l[1], l[2], l[3]);
}

// ---------------------------------------------------------------------------
// Pass 1: per-row online (m,Z) over a 512-wide k-slice.
// Grid: 2048 (rt = bid>>4 [early exit], kh = bid&15 -> XCD-sliced P locality).
// ---------------------------------------------------------------------------
__global__ __launch_bounds__(256, 3)
void pass1(const u16* __restrict__ Qh, const u16* __restrict__ Ql,
           const u16* __restrict__ Pht, const u16* __restrict__ Plt,
           const float* __restrict__ temp, const int* __restrict__ total_p,
           float* __restrict__ m_part, float* __restrict__ z_part) {
  int bid = blockIdx.x;
  int kh = bid & 15, rt = bid >> 4;
  int total = total_p[0];
  int row0 = rt * BM;
  if (row0 >= total) return;
  int tid = threadIdx.x;
  int wid = tid >> 6, lane = tid & 63;
  int wm = wid >> 1, wn = wid & 1;
  int fr = lane & 15, fq = lane >> 4;
  int psl = fq ^ ((fr >> 1) & 3);

  __shared__ u16 Ah[BM*32], Al[BM*32], Bh[BN*32], Bl[BN*32];   // 8KB each
  __shared__ float mloc[2][BM], zloc[2][BM];

  float invT = 1.0f / temp[0];

  // staging geometry: wave wid covers chunks [wid*128, wid*128+128)
  int c0 = wid*128 + lane, c1 = c0 + 64;
  int rl0 = c0 >> 2, rl1 = c1 >> 2;
  int sl0 = (c0 & 3) ^ ((rl0 >> 1) & 3);
  int sl1 = (c1 & 3) ^ ((rl1 >> 1) & 3);
  int gr0 = min(row0 + rl0, total - 1);
  int gr1 = min(row0 + rl1, total - 1);
  const u16* qh0 = Qh + (size_t)gr0*ND + sl0*8;
  const u16* qh1 = Qh + (size_t)gr1*ND + sl1*8;
  const u16* ql0 = Ql + (size_t)gr0*ND + sl0*8;
  const u16* ql1 = Ql + (size_t)gr1*ND + sl1*8;
  u16* dA0h = Ah + wid*1024;  u16* dA1h = Ah + wid*1024 + 512;
  u16* dA0l = Al + wid*1024;  u16* dA1l = Al + wid*1024 + 512;
  u16* dB0h = Bh + wid*1024;  u16* dB1h = Bh + wid*1024 + 512;
  u16* dB0l = Bl + wid*1024;  u16* dB1l = Bl + wid*1024 + 512;

  float mrun = -INFINITY, zrun = 0.f;   // meaningful for tid < BM

  for (int kt = 0; kt < KSLICE/BN; ++kt) {
    int ktg = kh * (KSLICE/BN) + kt;    // global 128-col tile index
    const u16* pb0h = Pht + (size_t)ktg*NDSTEP*4096 + (size_t)c0*8;
    const u16* pb1h = Pht + (size_t)ktg*NDSTEP*4096 + (size_t)c1*8;
    const u16* pb0l = Plt + (size_t)ktg*NDSTEP*4096 + (size_t)c0*8;
    const u16* pb1l = Plt + (size_t)ktg*NDSTEP*4096 + (size_t)c1*8;

    f32x4 acc[4][4];
#pragma unroll
    for (int i = 0; i < 4; ++i)
#pragma unroll
      for (int j = 0; j < 4; ++j) acc[i][j] = f32x4{0.f, 0.f, 0.f, 0.f};

    for (int dt = 0; dt < NDSTEP; ++dt) {
      __syncthreads();                  // prev frag reads done
      int dq = dt * 32;                 // Q element offset
      int dp = dt * 4096;               // P tile chunk offset (ushorts)
      gload16(qh0 + dq, dA0h);  gload16(qh1 + dq, dA1h);
      gload16(ql0 + dq, dA0l);  gload16(ql1 + dq, dA1l);
      gload16(pb0h + dp, dB0h); gload16(pb1h + dp, dB1h);
      gload16(pb0l + dp, dB0l); gload16(pb1l + dp, dB1l);
      __syncthreads();                  // tiles visible
      mfma_step(Ah, Al, Bh, Bl, wm, wn, fr, psl, acc);
    }

#pragma unroll
    for (int i = 0; i < 4; ++i)
#pragma unroll
      for (int j = 0; j < 4; ++j) acc[i][j] *= invT;

    // per-row (max, sumexp) within this 128-wide tile
#pragma unroll
    for (int mi = 0; mi < 4; ++mi)
#pragma unroll
      for (int r = 0; r < 4; ++r) {
        float vm = -INFINITY;
#pragma unroll
        for (int ni = 0; ni < 4; ++ni) vm = fmaxf(vm, acc[mi][ni][r]);
        vm = fmaxf(vm, __shfl_xor(vm, 1));
        vm = fmaxf(vm, __shfl_xor(vm, 2));
        vm = fmaxf(vm, __shfl_xor(vm, 4));
        vm = fmaxf(vm, __shfl_xor(vm, 8));
        float s = 0.f;
#pragma unroll
        for (int ni = 0; ni < 4; ++ni) s += __expf(acc[mi][ni][r] - vm);
        s += __shfl_xor(s, 1); s += __shfl_xor(s, 2);
        s += __shfl_xor(s, 4); s += __shfl_xor(s, 8);
        if (fr == 0) {
          int slot = wm*64 + mi*16 + fq*4 + r;
          mloc[wn][slot] = vm; zloc[wn][slot] = s;
        }
      }
    __syncthreads();
    if (tid < BM) {
      float m0 = mloc[0][tid], m1 = mloc[1][tid];
      float z0 = zloc[0][tid], z1 = zloc[1][tid];
      float mw = fmaxf(m0, m1);
      float zw = z0 * __expf(m0 - mw) + z1 * __expf(m1 - mw);
      float mn = fmaxf(mrun, mw);
      zrun = zrun * __expf(mrun - mn) + zw * __expf(mw - mn);
      mrun = mn;
    }
  }

  if (tid < BM && row0 + tid < total) {
    m_part[(size_t)kh * NM + row0 + tid] = mrun;
    z_part[(size_t)kh * NM + row0 + tid] = zrun;
  }
}

// ---------------------------------------------------------------------------
// Combine KSPLIT partials -> m, 1/Z per compacted row.
// ---------------------------------------------------------------------------
__global__ __launch_bounds__(256)
void combine(const float* __restrict__ m_part, const float* __restrict__ z_part,
             const int* __restrict__ total_p,
             float* __restrict__ m_c, float* __restrict__ iz_c) {
  int j = blockIdx.x * 256 + threadIdx.x;
  if (j >= total_p[0]) return;
  float m = -INFINITY;
#pragma unroll
  for (int k = 0; k < KSPLIT; ++k) m = fmaxf(m, m_part[(size_t)k*NM + j]);
  float z = 0.f;
#pragma unroll
  for (int k = 0; k < KSPLIT; ++k)
    z += z_part[(size_t)k*NM + j] * __expf(m_part[(size_t)k*NM + j] - m);
  m_c[j] = m;
  iz_c[j] = 1.0f / z;
}

// ---------------------------------------------------------------------------
// Pass 2: per (kt, b): recompute logits over batch rows, A=exp(x-m)/Z,
// column-max -> out. Grid 2048: kt = (bid&7)*8 + ((bid>>3)&7) (XCD-sliced),
// b = bid>>6.
// ---------------------------------------------------------------------------
__global__ __launch_bounds__(256, 3)
void pass2(const u16* __restrict__ Qh, const u16* __restrict__ Ql,
           const u16* __restrict__ Pht, const u16* __restrict__ Plt,
           const float* __restrict__ temp,
           const int* __restrict__ cntb, const int* __restrict__ offb,
           const float* __restrict__ m_c, const float* __restrict__ iz_c,
           float* __restrict__ out) {
  int bid = blockIdx.x;
  int kt = (bid & 7) * 8 + ((bid >> 3) & 7);
  int b = bid >> 6;
  int cb = cntb[b], ob = offb[b];
  int tid = threadIdx.x;
  if (cb == 0) { if (tid < BN) out[(size_t)b*NK + kt*BN + tid] = 0.f; return; }

  int wid = tid >> 6, lane = tid & 63;
  int wm = wid >> 1, wn = wid & 1;
  int fr = lane & 15, fq = lane >> 4;
  int psl = fq ^ ((fr >> 1) & 3);

  __shared__ u16 Ah[BM*32], Al[BM*32], Bh[BN*32], Bl[BN*32];
  __shared__ float mrow[BM], izrow[BM];
  __shared__ float red[2][BN];

  float invT = 1.0f / temp[0];

  int c0 = wid*128 + lane, c1 = c0 + 64;
  int rl0 = c0 >> 2, rl1 = c1 >> 2;
  int sl0 = (c0 & 3) ^ ((rl0 >> 1) & 3);
  int sl1 = (c1 & 3) ^ ((rl1 >> 1) & 3);
  u16* dA0h = Ah + wid*1024;  u16* dA1h = Ah + wid*1024 + 512;
  u16* dA0l = Al + wid*1024;  u16* dA1l = Al + wid*1024 + 512;
  u16* dB0h = Bh + wid*1024;  u16* dB1h = Bh + wid*1024 + 512;
  u16* dB0l = Bl + wid*1024;  u16* dB1l = Bl + wid*1024 + 512;

  const u16* pb0h = Pht + (size_t)kt*NDSTEP*4096 + (size_t)c0*8;
  const u16* pb1h = Pht + (size_t)kt*NDSTEP*4096 + (size_t)c1*8;
  const u16* pb0l = Plt + (size_t)kt*NDSTEP*4096 + (size_t)c0*8;
  const u16* pb1l = Plt + (size_t)kt*NDSTEP*4096 + (size_t)c1*8;

  float rc[4] = {0.f, 0.f, 0.f, 0.f};

  for (int t0 = 0; t0 < cb; t0 += BM) {
    if (tid < BM) {
      int j = min(t0 + tid, cb - 1);
      mrow[tid] = m_c[ob + j];
      izrow[tid] = (t0 + tid < cb) ? iz_c[ob + j] : 0.f;
    }
    int gr0 = ob + min(t0 + rl0, cb - 1);
    int gr1 = ob + min(t0 + rl1, cb - 1);
    const u16* qh0 = Qh + (size_t)gr0*ND + sl0*8;
    const u16* qh1 = Qh + (size_t)gr1*ND + sl1*8;
    const u16* ql0 = Ql + (size_t)gr0*ND + sl0*8;
    const u16* ql1 = Ql + (size_t)gr1*ND + sl1*8;

    f32x4 acc[4][4];
#pragma unroll
    for (int i = 0; i < 4; ++i)
#pragma unroll
      for (int j = 0; j < 4; ++j) acc[i][j] = f32x4{0.f, 0.f, 0.f, 0.f};

    for (int dt = 0; dt < NDSTEP; ++dt) {
      __syncthreads();
      int dq = dt * 32, dp = dt * 4096;
      gload16(qh0 + dq, dA0h);  gload16(qh1 + dq, dA1h);
      gload16(ql0 + dq, dA0l);  gload16(ql1 + dq, dA1l);
      gload16(pb0h + dp, dB0h); gload16(pb1h + dp, dB1h);
      gload16(pb0l + dp, dB0l); gload16(pb1l + dp, dB1l);
      __syncthreads();
      mfma_step(Ah, Al, Bh, Bl, wm, wn, fr, psl, acc);
    }

#pragma unroll
    for (int mi = 0; mi < 4; ++mi)
#pragma unroll
      for (int r = 0; r < 4; ++r) {
        int slot = wm*64 + mi*16 + fq*4 + r;
        float mv = mrow[slot], izv = izrow[slot];
#pragma unroll
        for (int ni = 0; ni < 4; ++ni)
          rc[ni] = fmaxf(rc[ni], __expf(acc[mi][ni][r]*invT - mv) * izv);
      }
    __syncthreads();   // protect mrow/izrow before next t0 overwrites
  }

  // reduce col-max across fq groups, then across wm via LDS
#pragma unroll
  for (int ni = 0; ni < 4; ++ni) {
    rc[ni] = fmaxf(rc[ni], __shfl_xor(rc[ni], 16));
    rc[ni] = fmaxf(rc[ni], __shfl_xor(rc[ni], 32));
  }
  if (fq == 0) {
#pragma unroll
    for (int ni = 0; ni < 4; ++ni) red[wm][wn*64 + ni*16 + fr] = rc[ni];
  }
  __syncthreads();
  if (tid < BN) out[(size_t)b*NK + kt*BN + tid] = fmaxf(red[0][tid], red[1][tid]);
}

// ---------------------------------------------------------------------------
// L2-normalize each batch row (length NK), torch-eps clamp.
// ---------------------------------------------------------------------------
__global__ __launch_bounds__(256)
void normalize_rows(float* __restrict__ out) {
  int b = blockIdx.x;
  int tid = threadIdx.x;
  float* row = out + (size_t)b * NK;
  float ss = 0.f;
  for (int i = tid; i < NK; i += 256) { float v = row[i]; ss = fmaf(v, v, ss); }
#pragma unroll
  for (int o = 1; o < 64; o <<= 1) ss += __shfl_xor(ss, o);
  __shared__ float wsum[4];
  int lane = tid & 63, wv = tid >> 6;
  if (lane == 0) wsum[wv] = ss;
  __syncthreads();
  float tot = wsum[0] + wsum[1] + wsum[2] + wsum[3];
  float inv = 1.0f / fmaxf(sqrtf(tot), 1e-12f);
  for (int i = tid; i < NK; i += 256) row[i] *= inv;
}

// ---------------------------------------------------------------------------
extern "C" void kernel_launch(void* const* d_in, const int* in_sizes, int n_in,
                              void* d_out, int out_size, void* d_ws, size_t ws_size,
                              hipStream_t stream) {
  const float* q    = (const float*)d_in[0];
  const float* p    = (const float*)d_in[1];
  const float* temp = (const float*)d_in[2];
  const int*   mask = (const int*)d_in[3];
  float* out = (float*)d_out;

  // ws layout (float offsets):
  //   [0)        m_c[NM]
  //   [NM)       iz_c[NM]
  //   [2NM)      m_part[16*NM]
  //   [18NM)     z_part[16*NM]
  //   [34NM)     vg[NM] (int)
  //   [35NM)     cntb[32] offb[32] total[1]   (ends at 35NM+65)
  //   [35NM+128) Qh | Ql | Pht | Plt  (bf16 arrays, ~75.5 MB)
  // NOTE: R3 bug was Qh at 35NM+64 overlapping `total` at 35NM+64 -> fixed.
  float* wsf    = (float*)d_ws;
  float* m_c    = wsf;
  float* iz_c   = wsf + NM;
  float* m_part = wsf + 2*NM;
  float* z_part = wsf + 2*NM + (size_t)KSPLIT*NM;
  int*   vg     = (int*)(wsf + 2*NM + (size_t)2*KSPLIT*NM);
  int*   cntb   = vg + NM;
  int*   offb   = cntb + NB;
  int*   total  = offb + NB;
  u16*   Qh     = (u16*)(wsf + (size_t)(2 + 2*KSPLIT + 1)*NM + 128);
  u16*   Ql     = Qh + (size_t)NM*ND;
  u16*   Pht    = Ql + (size_t)NM*ND;
  u16*   Plt    = Pht + (size_t)NK*ND;

  compact_all<<<1, 512, 0, stream>>>(mask, vg, cntb, offb, total);

  convert_q<<<(NM*(ND/8))/256, 256, 0, stream>>>(q, vg, total, Qh, Ql);
  convert_p<<<(64*NDSTEP*512)/256, 256, 0, stream>>>(p, Pht, Plt);

  pass1<<<(NM/BM)*KSPLIT, 256, 0, stream>>>(Qh, Ql, Pht, Plt, temp, total, m_part, z_part);

  combine<<<NM/256, 256, 0, stream>>>(m_part, z_part, total, m_c, iz_c);

  pass2<<<64*NB, 256, 0, stream>>>(Qh, Ql, Pht, Plt, temp, cntb, offb, m_c, iz_c, out);

  normalize_rows<<<NB, 256, 0, stream>>>(out);
}

// Round 5
// 757.230 us; speedup vs baseline: 7.8458x; 1.0214x over previous
//
#include <hip/hip_runtime.h>
#include <cmath>

#define NB 32
#define NL 512
#define ND 768
#define NK 8192
#define NM (NB*NL)        // 16384 max rows
#define BM 128
#define BN 128
#define NDSTEP (ND/32)    // 24 d-steps of BK=32
#define KSPLIT 16
#define KSLICE (NK/KSPLIT)   // 512 -> 4 column tiles of 128 per pass1 block

typedef __attribute__((ext_vector_type(8))) short bf16x8;
typedef __attribute__((ext_vector_type(4))) float f32x4;
typedef unsigned short u16;

// async global->LDS, 16B per lane. dest must be wave-uniform; HW adds lane*16.
__device__ __forceinline__ void gload16(const void* g, void* s) {
  __builtin_amdgcn_global_load_lds(
      (const __attribute__((address_space(1))) char*)g,
      (__attribute__((address_space(3))) char*)s, 16, 0, 0);
}

// split fp32 pair into hi/lo bf16 pairs (packed)
__device__ __forceinline__ void split_pk(float x0, float x1, unsigned &h, unsigned &l) {
  unsigned hp;
  asm("v_cvt_pk_bf16_f32 %0, %1, %2" : "=v"(hp) : "v"(x0), "v"(x1));
  union { unsigned u; float f; } f0, f1;
  f0.u = hp << 16;
  f1.u = hp & 0xffff0000u;
  unsigned lp;
  float r0 = x0 - f0.f, r1 = x1 - f1.f;
  asm("v_cvt_pk_bf16_f32 %0, %1, %2" : "=v"(lp) : "v"(r0), "v"(r1));
  h = hp; l = lp;
}

// One BK=32 step: 16 ds_read_b128 + 48 MFMAs (3-product split-bf16).
// psl = fq ^ ((fr>>1)&3) : physical slot for this lane's logical k-slot fq.
__device__ __forceinline__ void mfma_step(const u16* Ah, const u16* Al,
                                          const u16* Bh, const u16* Bl,
                                          int wm, int wn, int fr, int psl,
                                          f32x4 acc[4][4]) {
  bf16x8 aH[4], aL[4], bH[4], bL[4];
#pragma unroll
  for (int i = 0; i < 4; ++i) {
    int ar = (wm*64 + i*16 + fr)*32 + psl*8;
    int br = (wn*64 + i*16 + fr)*32 + psl*8;
    aH[i] = *(const bf16x8*)&Ah[ar];
    aL[i] = *(const bf16x8*)&Al[ar];
    bH[i] = *(const bf16x8*)&Bh[br];
    bL[i] = *(const bf16x8*)&Bl[br];
  }
  __builtin_amdgcn_s_setprio(1);
#pragma unroll
  for (int mi = 0; mi < 4; ++mi)
#pragma unroll
    for (int ni = 0; ni < 4; ++ni) {
      acc[mi][ni] = __builtin_amdgcn_mfma_f32_16x16x32_bf16(aH[mi], bH[ni], acc[mi][ni], 0, 0, 0);
      acc[mi][ni] = __builtin_amdgcn_mfma_f32_16x16x32_bf16(aH[mi], bL[ni], acc[mi][ni], 0, 0, 0);
      acc[mi][ni] = __builtin_amdgcn_mfma_f32_16x16x32_bf16(aL[mi], bH[ni], acc[mi][ni], 0, 0, 0);
    }
  __builtin_amdgcn_s_setprio(0);
}

// ---------------------------------------------------------------------------
// Kernel 0: global compaction of valid rows (batch-major).
// ---------------------------------------------------------------------------
__global__ __launch_bounds__(512)
void compact_all(const int* __restrict__ mask, int* __restrict__ vg,
                 int* __restrict__ cntb, int* __restrict__ offb,
                 int* __restrict__ total) {
  __shared__ int wcnt[8], woff[8];
  __shared__ int base;
  int t = threadIdx.x;
  if (t == 0) base = 0;
  __syncthreads();
  for (int b = 0; b < NB; ++b) {
    int v = (mask[b*NL + t] != 0) ? 1 : 0;
    unsigned long long bal = __ballot(v);
    int lane = t & 63, wv = t >> 6;
    int pos = __popcll(bal & ((1ull << lane) - 1ull));
    if (lane == 0) wcnt[wv] = __popcll(bal);
    __syncthreads();
    if (t == 0) {
      int s = 0;
#pragma unroll
      for (int w = 0; w < 8; ++w) { woff[w] = s; s += wcnt[w]; }
      cntb[b] = s; offb[b] = base;
    }
    __syncthreads();
    if (v) vg[base + woff[wv] + pos] = b*NL + t;
    __syncthreads();
    if (t == 0) base += cntb[b];
    __syncthreads();
  }
  if (t == 0) total[0] = base;
}

// ---------------------------------------------------------------------------
// Convert Q -> compacted-row-major bf16 hi/lo.
// ---------------------------------------------------------------------------
__global__ __launch_bounds__(256)
void convert_q(const float* __restrict__ q, const int* __restrict__ vg,
               const int* __restrict__ total_p,
               u16* __restrict__ Qh, u16* __restrict__ Ql) {
  int total = total_p[0];
  int cid = blockIdx.x * 256 + threadIdx.x;       // chunk of 8 elements
  int row = cid / (ND/8), c = cid % (ND/8);
  if (row >= total) return;
  const float* src = q + (size_t)vg[row] * ND + c*8;
  float4 v0 = ((const float4*)src)[0], v1 = ((const float4*)src)[1];
  unsigned h[4], l[4];
  split_pk(v0.x, v0.y, h[0], l[0]); split_pk(v0.z, v0.w, h[1], l[1]);
  split_pk(v1.x, v1.y, h[2], l[2]); split_pk(v1.z, v1.w, h[3], l[3]);
  size_t o = (size_t)row * ND + c*8;
  *(uint4*)(Qh + o) = make_uint4(h[0], h[1], h[2], h[3]);
  *(uint4*)(Ql + o) = make_uint4(l[0], l[1], l[2], l[3]);
}

// ---------------------------------------------------------------------------
// Convert P -> tiled + pre-swizzled bf16 hi/lo.
// Tile (kt, dt) = 128 rows x 32 d, stored as 512 chunks of 16B; chunk
// (r, s_phys) holds logical d-slot s_phys ^ ((r>>1)&3).
// ---------------------------------------------------------------------------
__global__ __launch_bounds__(256)
void convert_p(const float* __restrict__ p,
               u16* __restrict__ Pht, u16* __restrict__ Plt) {
  int cid = blockIdx.x * 256 + threadIdx.x;        // 64*24*512 chunks
  int kt = cid / (NDSTEP*512);
  int rem = cid % (NDSTEP*512);
  int dt = rem / 512, c = rem % 512;
  int r = c >> 2, sp = c & 3;
  int sl = sp ^ ((r >> 1) & 3);
  const float* src = p + (size_t)(kt*128 + r) * ND + dt*32 + sl*8;
  float4 v0 = ((const float4*)src)[0], v1 = ((const float4*)src)[1];
  unsigned h[4], l[4];
  split_pk(v0.x, v0.y, h[0], l[0]); split_pk(v0.z, v0.w, h[1], l[1]);
  split_pk(v1.x, v1.y, h[2], l[2]); split_pk(v1.z, v1.w, h[3], l[3]);
  size_t o = (size_t)cid * 8;
  *(uint4*)(Pht + o) = make_uint4(h[0], h[1], h[2], h[3]);
  *(uint4*)(Plt + o) = make_uint4(l[0], l[1], l[2], l[3]);
}

// ---------------------------------------------------------------------------
// Pass 1: per-row online (m,Z) over a 512-wide k-slice. Double-buffered
// 2-phase pipeline: stage(t+1) || mfma(t), one barrier per step.
// Grid: 2048 (rt = bid>>4 [early exit], kh = bid&15 -> XCD-sliced P locality).
// ---------------------------------------------------------------------------
__global__ __launch_bounds__(256, 2)
void pass1(const u16* __restrict__ Qh, const u16* __restrict__ Ql,
           const u16* __restrict__ Pht, const u16* __restrict__ Plt,
           const float* __restrict__ temp, const int* __restrict__ total_p,
           float* __restrict__ m_part, float* __restrict__ z_part) {
  int bid = blockIdx.x;
  int kh = bid & 15, rt = bid >> 4;
  int total = total_p[0];
  int row0 = rt * BM;
  if (row0 >= total) return;
  int tid = threadIdx.x;
  int wid = tid >> 6, lane = tid & 63;
  int wm = wid >> 1, wn = wid & 1;
  int fr = lane & 15, fq = lane >> 4;
  int psl = fq ^ ((fr >> 1) & 3);

  __shared__ u16 Ah[2][BM*32], Al[2][BM*32], Bh[2][BN*32], Bl[2][BN*32]; // 64KB
  __shared__ float mloc[2][BM], zloc[2][BM];

  float invT = 1.0f / temp[0];

  // staging geometry: wave wid covers chunks [wid*128, wid*128+128)
  int c0 = wid*128 + lane, c1 = c0 + 64;
  int rl0 = c0 >> 2, rl1 = c1 >> 2;
  int sl0 = (c0 & 3) ^ ((rl0 >> 1) & 3);
  int sl1 = (c1 & 3) ^ ((rl1 >> 1) & 3);
  int gr0 = min(row0 + rl0, total - 1);
  int gr1 = min(row0 + rl1, total - 1);
  const u16* qh0 = Qh + (size_t)gr0*ND + sl0*8;
  const u16* qh1 = Qh + (size_t)gr1*ND + sl1*8;
  const u16* ql0 = Ql + (size_t)gr0*ND + sl0*8;
  const u16* ql1 = Ql + (size_t)gr1*ND + sl1*8;

  // stage step (ktg global col-tile, dt) into buffer bf
  auto stage = [&](int bf, int ktg, int dt) {
    int dq = dt * 32;
    size_t pofs = (size_t)ktg*NDSTEP*4096 + (size_t)dt*4096;
    const u16* ph = Pht + pofs;
    const u16* pl = Plt + pofs;
    int w = wid*1024;
    gload16(qh0 + dq, &Ah[bf][w]);        gload16(qh1 + dq, &Ah[bf][w+512]);
    gload16(ql0 + dq, &Al[bf][w]);        gload16(ql1 + dq, &Al[bf][w+512]);
    gload16(ph + (size_t)c0*8, &Bh[bf][w]); gload16(ph + (size_t)c1*8, &Bh[bf][w+512]);
    gload16(pl + (size_t)c0*8, &Bl[bf][w]); gload16(pl + (size_t)c1*8, &Bl[bf][w+512]);
  };

  float mrun = -INFINITY, zrun = 0.f;   // meaningful for tid < BM
  int ktg0 = kh * (KSLICE/BN);

  stage(0, ktg0, 0);
  __syncthreads();
  int buf = 0;

  for (int kt = 0; kt < KSLICE/BN; ++kt) {
    f32x4 acc[4][4];
#pragma unroll
    for (int i = 0; i < 4; ++i)
#pragma unroll
      for (int j = 0; j < 4; ++j) acc[i][j] = f32x4{0.f, 0.f, 0.f, 0.f};

    for (int dt = 0; dt < NDSTEP; ++dt) {
      if (dt < NDSTEP-1)            stage(buf^1, ktg0 + kt, dt+1);
      else if (kt < KSLICE/BN - 1)  stage(buf^1, ktg0 + kt + 1, 0);
      mfma_step(Ah[buf], Al[buf], Bh[buf], Bl[buf], wm, wn, fr, psl, acc);
      __syncthreads();              // drains staged loads; protects buf reuse
      buf ^= 1;
    }

#pragma unroll
    for (int i = 0; i < 4; ++i)
#pragma unroll
      for (int j = 0; j < 4; ++j) acc[i][j] *= invT;

    // per-row (max, sumexp) within this 128-wide tile
#pragma unroll
    for (int mi = 0; mi < 4; ++mi)
#pragma unroll
      for (int r = 0; r < 4; ++r) {
        float vm = -INFINITY;
#pragma unroll
        for (int ni = 0; ni < 4; ++ni) vm = fmaxf(vm, acc[mi][ni][r]);
        vm = fmaxf(vm, __shfl_xor(vm, 1));
        vm = fmaxf(vm, __shfl_xor(vm, 2));
        vm = fmaxf(vm, __shfl_xor(vm, 4));
        vm = fmaxf(vm, __shfl_xor(vm, 8));
        float s = 0.f;
#pragma unroll
        for (int ni = 0; ni < 4; ++ni) s += __expf(acc[mi][ni][r] - vm);
        s += __shfl_xor(s, 1); s += __shfl_xor(s, 2);
        s += __shfl_xor(s, 4); s += __shfl_xor(s, 8);
        if (fr == 0) {
          int slot = wm*64 + mi*16 + fq*4 + r;
          mloc[wn][slot] = vm; zloc[wn][slot] = s;
        }
      }
    __syncthreads();
    if (tid < BM) {
      float m0 = mloc[0][tid], m1 = mloc[1][tid];
      float z0 = zloc[0][tid], z1 = zloc[1][tid];
      float mw = fmaxf(m0, m1);
      float zw = z0 * __expf(m0 - mw) + z1 * __expf(m1 - mw);
      float mn = fmaxf(mrun, mw);
      zrun = zrun * __expf(mrun - mn) + zw * __expf(mw - mn);
      mrun = mn;
    }
    __syncthreads();   // mloc/zloc reusable next kt
  }

  if (tid < BM && row0 + tid < total) {
    m_part[(size_t)kh * NM + row0 + tid] = mrun;
    z_part[(size_t)kh * NM + row0 + tid] = zrun;
  }
}

// ---------------------------------------------------------------------------
// Combine KSPLIT partials -> m, 1/Z per compacted row.
// ---------------------------------------------------------------------------
__global__ __launch_bounds__(256)
void combine(const float* __restrict__ m_part, const float* __restrict__ z_part,
             const int* __restrict__ total_p,
             float* __restrict__ m_c, float* __restrict__ iz_c) {
  int j = blockIdx.x * 256 + threadIdx.x;
  if (j >= total_p[0]) return;
  float m = -INFINITY;
#pragma unroll
  for (int k = 0; k < KSPLIT; ++k) m = fmaxf(m, m_part[(size_t)k*NM + j]);
  float z = 0.f;
#pragma unroll
  for (int k = 0; k < KSPLIT; ++k)
    z += z_part[(size_t)k*NM + j] * __expf(m_part[(size_t)k*NM + j] - m);
  m_c[j] = m;
  iz_c[j] = 1.0f / z;
}

// ---------------------------------------------------------------------------
// Pass 2: per (kt, b): recompute logits over batch rows, A=exp(x-m)/Z,
// column-max -> out. Same 2-phase pipeline; prefetch across row-tiles.
// Grid 2048: kt = (bid&7)*8 + ((bid>>3)&7) (XCD-sliced), b = bid>>6.
// ---------------------------------------------------------------------------
__global__ __launch_bounds__(256, 2)
void pass2(const u16* __restrict__ Qh, const u16* __restrict__ Ql,
           const u16* __restrict__ Pht, const u16* __restrict__ Plt,
           const float* __restrict__ temp,
           const int* __restrict__ cntb, const int* __restrict__ offb,
           const float* __restrict__ m_c, const float* __restrict__ iz_c,
           float* __restrict__ out) {
  int bid = blockIdx.x;
  int kt = (bid & 7) * 8 + ((bid >> 3) & 7);
  int b = bid >> 6;
  int cb = cntb[b], ob = offb[b];
  int tid = threadIdx.x;
  if (cb == 0) { if (tid < BN) out[(size_t)b*NK + kt*BN + tid] = 0.f; return; }

  int wid = tid >> 6, lane = tid & 63;
  int wm = wid >> 1, wn = wid & 1;
  int fr = lane & 15, fq = lane >> 4;
  int psl = fq ^ ((fr >> 1) & 3);

  __shared__ u16 Ah[2][BM*32], Al[2][BM*32], Bh[2][BN*32], Bl[2][BN*32];
  __shared__ float mrow[BM], izrow[BM];
  __shared__ float red[2][BN];

  float invT = 1.0f / temp[0];

  int c0 = wid*128 + lane, c1 = c0 + 64;
  int rl0 = c0 >> 2, rl1 = c1 >> 2;
  int sl0 = (c0 & 3) ^ ((rl0 >> 1) & 3);
  int sl1 = (c1 & 3) ^ ((rl1 >> 1) & 3);

  // Q source pointers for current row-tile (updated at tile switch)
  const u16 *qh0, *qh1, *ql0, *ql1;
  auto setq = [&](int t0) {
    int g0 = ob + min(t0 + rl0, cb - 1);
    int g1 = ob + min(t0 + rl1, cb - 1);
    qh0 = Qh + (size_t)g0*ND + sl0*8;
    qh1 = Qh + (size_t)g1*ND + sl1*8;
    ql0 = Ql + (size_t)g0*ND + sl0*8;
    ql1 = Ql + (size_t)g1*ND + sl1*8;
  };
  auto stage = [&](int bf, int dt) {
    int dq = dt * 32;
    size_t pofs = (size_t)kt*NDSTEP*4096 + (size_t)dt*4096;
    const u16* ph = Pht + pofs;
    const u16* pl = Plt + pofs;
    int w = wid*1024;
    gload16(qh0 + dq, &Ah[bf][w]);        gload16(qh1 + dq, &Ah[bf][w+512]);
    gload16(ql0 + dq, &Al[bf][w]);        gload16(ql1 + dq, &Al[bf][w+512]);
    gload16(ph + (size_t)c0*8, &Bh[bf][w]); gload16(ph + (size_t)c1*8, &Bh[bf][w+512]);
    gload16(pl + (size_t)c0*8, &Bl[bf][w]); gload16(pl + (size_t)c1*8, &Bl[bf][w+512]);
  };

  float rc[4] = {0.f, 0.f, 0.f, 0.f};

  setq(0);
  stage(0, 0);
  __syncthreads();
  int buf = 0;

  for (int t0 = 0; t0 < cb; t0 += BM) {
    if (tid < BM) {
      int j = min(t0 + tid, cb - 1);
      mrow[tid] = m_c[ob + j];
      izrow[tid] = (t0 + tid < cb) ? iz_c[ob + j] : 0.f;
    }

    f32x4 acc[4][4];
#pragma unroll
    for (int i = 0; i < 4; ++i)
#pragma unroll
      for (int j = 0; j < 4; ++j) acc[i][j] = f32x4{0.f, 0.f, 0.f, 0.f};

    for (int dt = 0; dt < NDSTEP; ++dt) {
      if (dt < NDSTEP-1) {
        stage(buf^1, dt+1);
      } else if (t0 + BM < cb) {
        setq(t0 + BM);               // advance Q pointers to next row-tile
        stage(buf^1, 0);
      }
      mfma_step(Ah[buf], Al[buf], Bh[buf], Bl[buf], wm, wn, fr, psl, acc);
      __syncthreads();
      buf ^= 1;
    }

#pragma unroll
    for (int mi = 0; mi < 4; ++mi)
#pragma unroll
      for (int r = 0; r < 4; ++r) {
        int slot = wm*64 + mi*16 + fq*4 + r;
        float mv = mrow[slot], izv = izrow[slot];
#pragma unroll
        for (int ni = 0; ni < 4; ++ni)
          rc[ni] = fmaxf(rc[ni], __expf(acc[mi][ni][r]*invT - mv) * izv);
      }
    __syncthreads();   // protect mrow/izrow before next t0 overwrites
  }

  // reduce col-max across fq groups, then across wm via LDS
#pragma unroll
  for (int ni = 0; ni < 4; ++ni) {
    rc[ni] = fmaxf(rc[ni], __shfl_xor(rc[ni], 16));
    rc[ni] = fmaxf(rc[ni], __shfl_xor(rc[ni], 32));
  }
  if (fq == 0) {
#pragma unroll
    for (int ni = 0; ni < 4; ++ni) red[wm][wn*64 + ni*16 + fr] = rc[ni];
  }
  __syncthreads();
  if (tid < BN) out[(size_t)b*NK + kt*BN + tid] = fmaxf(red[0][tid], red[1][tid]);
}

// ---------------------------------------------------------------------------
// L2-normalize each batch row (length NK), torch-eps clamp.
// ---------------------------------------------------------------------------
__global__ __launch_bounds__(256)
void normalize_rows(float* __restrict__ out) {
  int b = blockIdx.x;
  int tid = threadIdx.x;
  float* row = out + (size_t)b * NK;
  float ss = 0.f;
  for (int i = tid; i < NK; i += 256) { float v = row[i]; ss = fmaf(v, v, ss); }
#pragma unroll
  for (int o = 1; o < 64; o <<= 1) ss += __shfl_xor(ss, o);
  __shared__ float wsum[4];
  int lane = tid & 63, wv = tid >> 6;
  if (lane == 0) wsum[wv] = ss;
  __syncthreads();
  float tot = wsum[0] + wsum[1] + wsum[2] + wsum[3];
  float inv = 1.0f / fmaxf(sqrtf(tot), 1e-12f);
  for (int i = tid; i < NK; i += 256) row[i] *= inv;
}

// ---------------------------------------------------------------------------
extern "C" void kernel_launch(void* const* d_in, const int* in_sizes, int n_in,
                              void* d_out, int out_size, void* d_ws, size_t ws_size,
                              hipStream_t stream) {
  const float* q    = (const float*)d_in[0];
  const float* p    = (const float*)d_in[1];
  const float* temp = (const float*)d_in[2];
  const int*   mask = (const int*)d_in[3];
  float* out = (float*)d_out;

  // ws layout (float offsets):
  //   [0)        m_c[NM]
  //   [NM)       iz_c[NM]
  //   [2NM)      m_part[16*NM]
  //   [18NM)     z_part[16*NM]
  //   [34NM)     vg[NM] (int)
  //   [35NM)     cntb[32] offb[32] total[1]   (ends at 35NM+65)
  //   [35NM+128) Qh | Ql | Pht | Plt  (bf16 arrays, ~75.5 MB)
  float* wsf    = (float*)d_ws;
  float* m_c    = wsf;
  float* iz_c   = wsf + NM;
  float* m_part = wsf + 2*NM;
  float* z_part = wsf + 2*NM + (size_t)KSPLIT*NM;
  int*   vg     = (int*)(wsf + 2*NM + (size_t)2*KSPLIT*NM);
  int*   cntb   = vg + NM;
  int*   offb   = cntb + NB;
  int*   total  = offb + NB;
  u16*   Qh     = (u16*)(wsf + (size_t)(2 + 2*KSPLIT + 1)*NM + 128);
  u16*   Ql     = Qh + (size_t)NM*ND;
  u16*   Pht    = Ql + (size_t)NM*ND;
  u16*   Plt    = Pht + (size_t)NK*ND;

  compact_all<<<1, 512, 0, stream>>>(mask, vg, cntb, offb, total);

  convert_q<<<(NM*(ND/8))/256, 256, 0, stream>>>(q, vg, total, Qh, Ql);
  convert_p<<<(64*NDSTEP*512)/256, 256, 0, stream>>>(p, Pht, Plt);

  pass1<<<(NM/BM)*KSPLIT, 256, 0, stream>>>(Qh, Ql, Pht, Plt, temp, total, m_part, z_part);

  combine<<<NM/256, 256, 0, stream>>>(m_part, z_part, total, m_c, iz_c);

  pass2<<<64*NB, 256, 0, stream>>>(Qh, Ql, Pht, Plt, temp, cntb, offb, m_c, iz_c, out);

  normalize_rows<<<NB, 256, 0, stream>>>(out);
}